// Round 4
// baseline (148.076 us; speedup 1.0000x reference)
//
#include <hip/hip_runtime.h>
#include <hip/hip_bf16.h>

typedef __bf16 bf16x8 __attribute__((ext_vector_type(8)));
typedef float  f32x4  __attribute__((ext_vector_type(4)));

// ---------------------------------------------------------------------------
// Stage 1: qkv = kern_tok @ qkv_w + qkv_b ; split into q(scaled),k,v
// ---------------------------------------------------------------------------
__global__ __launch_bounds__(192) void qkv_kernel(
    const float* __restrict__ conv_w, const float* __restrict__ qkv_w,
    const float* __restrict__ qkv_b,
    float* __restrict__ qv, float* __restrict__ kvv, float* __restrict__ vv)
{
    __shared__ float tok[64];
    const int bid = blockIdx.x;          // co*36 + s
    const int co = bid / 36, s = bid - co * 36;
    const int w = s / 9, p = s - w * 9;
    const int t = threadIdx.x;           // 192
    if (t < 64) tok[t] = conv_w[(((w * 64 + co) * 64 + t) * 9) + p];
    __syncthreads();
    float acc = qkv_b[t];
#pragma unroll 8
    for (int ci = 0; ci < 64; ++ci) acc += tok[ci] * qkv_w[ci * 192 + t];
    const int trip = t >> 6, rem = t & 63, h = rem >> 3, d = rem & 7;
    if (trip == 0) acc *= 0.35355339059327373f;   // hd^-0.5, hd=8
    float* dst = (trip == 0) ? qv : ((trip == 1) ? kvv : vv);
    dst[((co * 8 + h) * 36 + s) * 8 + d] = acc;
}

// ---------------------------------------------------------------------------
// Stage 2: attention per (co, head): softmax(q k^T) v  -> ao[co][s][h*8+d]
// ---------------------------------------------------------------------------
__global__ __launch_bounds__(64) void attn_kernel(
    const float* __restrict__ qv, const float* __restrict__ kvv,
    const float* __restrict__ vv, float* __restrict__ ao)
{
    __shared__ float kl[288], vl[288];
    const int bid = blockIdx.x;          // co*8 + h
    const int t = threadIdx.x;           // 64
    const float* kb = kvv + bid * 288;
    const float* vb = vv + bid * 288;
    for (int i = t; i < 288; i += 64) { kl[i] = kb[i]; vl[i] = vb[i]; }
    __syncthreads();
    if (t < 36) {
        float q[8];
        const float* qb = qv + bid * 288 + t * 8;
#pragma unroll
        for (int d = 0; d < 8; ++d) q[d] = qb[d];
        float sc[36];
        float mx = -1e30f;
#pragma unroll
        for (int u = 0; u < 36; ++u) {
            float a = 0.f;
#pragma unroll
            for (int d = 0; d < 8; ++d) a += q[d] * kl[u * 8 + d];
            sc[u] = a;
            mx = fmaxf(mx, a);
        }
        float sum = 0.f;
        float o[8] = {0.f,0.f,0.f,0.f,0.f,0.f,0.f,0.f};
#pragma unroll
        for (int u = 0; u < 36; ++u) {
            float e = expf(sc[u] - mx);
            sum += e;
#pragma unroll
            for (int d = 0; d < 8; ++d) o[d] += e * vl[u * 8 + d];
        }
        const float inv = 1.0f / sum;
        const int co = bid >> 3, h = bid & 7;
        float* dst = ao + (co * 36 + t) * 64 + h * 8;
#pragma unroll
        for (int d = 0; d < 8; ++d) dst[d] = o[d] * inv;
    }
}

// ---------------------------------------------------------------------------
// Stage 3: proj + SE + write bf16 kernels.
// kout layout: [((h*4 + w)*9 + p)][co][ci32]  (4 KB chunks; for fixed (h,w)
// taps p..p+1 are CONTIGUOUS 8 KB -> conv stages 2 taps per global_load_lds
// round).
// ---------------------------------------------------------------------------
__global__ __launch_bounds__(64) void proj_se_kernel(
    const float* __restrict__ ao, const float* __restrict__ proj_w,
    const float* __restrict__ proj_b,
    const float* __restrict__ se_w1, const float* __restrict__ se_b1,
    const float* __restrict__ se_w2, const float* __restrict__ se_b2,
    ushort* __restrict__ kout)
{
    __shared__ float al[9][64];
    __shared__ float pool[64];
    __shared__ float hb[4];
    const int bid = blockIdx.x;          // w*64 + co
    const int w = bid >> 6, co = bid & 63;
    const int t = threadIdx.x;           // 64 (= ci)
    for (int i = t; i < 576; i += 64) {
        int p = i >> 6, j = i & 63;
        al[p][j] = ao[(co * 36 + w * 9 + p) * 64 + j];
    }
    __syncthreads();
    float kv[9];
#pragma unroll
    for (int p = 0; p < 9; ++p) {
        float a = proj_b[t];
#pragma unroll 8
        for (int j = 0; j < 64; ++j) a += al[p][j] * proj_w[j * 64 + t];
        kv[p] = a;
    }
    float pl = 0.f;
#pragma unroll
    for (int p = 0; p < 9; ++p) pl += kv[p];
    pool[t] = pl * (1.0f / 9.0f);
    __syncthreads();
    if (t < 4) {
        float hh = se_b1[w * 4 + t];
#pragma unroll 8
        for (int c = 0; c < 64; ++c) hh += pool[c] * se_w1[(w * 4 + t) * 64 + c];
        hb[t] = fmaxf(hh, 0.0f);
    }
    __syncthreads();
    float z = se_b2[w * 64 + t];
#pragma unroll
    for (int d = 0; d < 4; ++d) z += hb[d] * se_w2[(w * 64 + t) * 4 + d];
    const float sg = 1.0f / (1.0f + expf(-z));
    const int hhalf = t >> 5, ci32 = t & 31;
#pragma unroll
    for (int p = 0; p < 9; ++p) {
        __hip_bfloat16 hv = __float2bfloat16(kv[p] * sg);
        kout[(((hhalf * 4 + w) * 9) + p) * 2048 + co * 32 + ci32] = *(const ushort*)&hv;
    }
}

// ---------------------------------------------------------------------------
// Stage 4: dynamic per-window 3x3 conv, implicit GEMM, bf16 MFMA.
// Tile 16x16 px, N=64 co, K = 2 ci-halves x 9 taps, 10 stages of <=2 taps.
//
// Round-4 changes (both theory-driven from R3 counters):
//  1. LDS XOR-swizzle on ALL traffic. 64 B/px rows cover only half the 32
//     banks, so every unswizzled Af/Kf read phase was 8-way conflicted
//     (SQ_LDS_BANK_CONFLICT=4.7M => ~67 us/CU of LDS-pipe serialization).
//     Swizzle: chunk16 ^= ((row>>1)&3)<<4 (bijective, in-row). For the
//     global_load_lds-filled kern buffer the swizzle is applied on the
//     GLOBAL source address (linear LDS dest), per the both-sides rule.
//  2. LDS-transpose epilogue. R3's NT 16B/lane stores gave WRITE_SIZE
//     273 MB = 2.04x ideal (NT granule amplification). Now each wave
//     scatters acc into a private 4 KB LDS region (row=pixel, swizzled),
//     reads back lane-contiguous chunks, and NT-stores 1 KB fully
//     contiguous per instruction (4 px rows x 256 B) -> full-line writes,
//     no amplification, no L2 pollution.
// ---------------------------------------------------------------------------
__global__ __launch_bounds__(256, 4) void conv_kernel(
    const float* __restrict__ x, const ushort* __restrict__ kern,
    float* __restrict__ out)
{
    __shared__ alignas(16) ushort in_lds[18 * 18 * 32];   // 20736 B
    __shared__ alignas(16) ushort kn_lds[2 * 4096];       // 16384 B (2 x 8KB)

    const int tid = threadIdx.x;

    // ---- XCD-chunked bijective remap: XCD k processes nb in [k*256,(k+1)*256)
    const int bid = blockIdx.x;                 // 0..2047, xcd = bid & 7
    const int nb  = ((bid & 7) << 8) + (bid >> 3);
    const int bz  = nb >> 6;                    // (w*8+b), 4 per XCD
    const int rem = nb & 63;
    const int i0  = (rem >> 3) << 4;
    const int j0  = (rem & 7) << 4;
    const int w = bz >> 3, b = bz & 7;
    const int gi = w >> 1, gj = w & 1;

    const int wv   = tid >> 6;
    const int lane = tid & 63;
    const int l15  = lane & 15;
    const int hi4  = lane >> 4;        // 0..3

    // ---- async kern stage. LDS dest is LINEAR (global_load_lds rule);
    // the read-side swizzle (chunk ^ ((co>>1)&3)<<4) is realized by
    // pre-swizzling the per-lane GLOBAL source offset: for dest lane*16,
    // co=lane>>2 -> (co>>1)&3 == (lane>>3)&3 for every (o, +1024) case.
    const char* kern_b = (const char*)kern;
    const int ksrc = (lane << 4) ^ (((lane >> 3) & 3) << 4);
    auto stage_kern = [&](int sg, int buf) {
        const int h = sg / 5, j = sg % 5;
        const int ntap = (j == 4) ? 1 : 2;
        const char* gs = kern_b + (size_t)((((h * 4 + w) * 9) + 2 * j) << 12);
        char* ld = (char*)kn_lds + (buf << 13);
        if (ntap == 2) {
            const int o = wv << 11;
            __builtin_amdgcn_global_load_lds(
                (const __attribute__((address_space(1))) unsigned int*)(gs + o + ksrc),
                (__attribute__((address_space(3))) unsigned int*)(ld + o), 16, 0, 0);
            __builtin_amdgcn_global_load_lds(
                (const __attribute__((address_space(1))) unsigned int*)(gs + o + 1024 + ksrc),
                (__attribute__((address_space(3))) unsigned int*)(ld + o + 1024), 16, 0, 0);
        } else {
            const int o = wv << 10;
            __builtin_amdgcn_global_load_lds(
                (const __attribute__((address_space(1))) unsigned int*)(gs + o + ksrc),
                (__attribute__((address_space(3))) unsigned int*)(ld + o), 16, 0, 0);
        }
    };

    // ---- input staging, one ci-half: 18x18 px, 32 ch, fp32->bf16.
    // 8 thr/px; 11 unconditional clamped loads, then cndmask-zero+cvt+write.
    // ds_write position: (pp<<6) + ((cc*2) ^ ((pp>>1)&3)<<4)  [swizzled]
    auto stage_input = [&](int h) {
        const int cc = (tid & 7) << 2;     // channel-in-half 0..28
        const int p0 = tid >> 3;           // 0..31
        float4 v[11];
        unsigned okm = 0;
#pragma unroll
        for (int k = 0; k < 11; ++k) {
            const int pp = p0 + (k << 5);              // <= 351
            const int ppc = pp < 323 ? pp : 323;
            const int r = ppc / 18, q = ppc - r * 18;
            const int iy = i0 - 1 + r, jx = j0 - 1 + q;
            const bool ok = (pp < 324) & (iy >= 0) & (iy < 128) & (jx >= 0) & (jx < 128);
            const int iyc = iy < 0 ? 0 : (iy > 127 ? 127 : iy);
            const int jxc = jx < 0 ? 0 : (jx > 127 ? 127 : jx);
            const size_t xi = (((size_t)b << 16) +
                               (size_t)(gi * 128 + iyc) * 256 + (size_t)(gj * 128 + jxc)) * 64 +
                              h * 32 + cc;
            v[k] = *(const float4*)(x + xi);
            okm |= (unsigned)ok << k;
        }
#pragma unroll
        for (int k = 0; k < 11; ++k) {
            const int pp = p0 + (k << 5);
            if (pp < 324) {
                float4 z = (okm >> k) & 1 ? v[k] : make_float4(0.f, 0.f, 0.f, 0.f);
                union { ushort4 u; ushort h4[4]; } tmp;
                __hip_bfloat16 b0 = __float2bfloat16(z.x); tmp.h4[0] = *(const ushort*)&b0;
                __hip_bfloat16 b1 = __float2bfloat16(z.y); tmp.h4[1] = *(const ushort*)&b1;
                __hip_bfloat16 b2 = __float2bfloat16(z.z); tmp.h4[2] = *(const ushort*)&b2;
                __hip_bfloat16 b3 = __float2bfloat16(z.w); tmp.h4[3] = *(const ushort*)&b3;
                const int sw = ((cc << 1) ^ (((pp >> 1) & 3) << 4));
                *(ushort4*)((char*)in_lds + ((pp << 6) + sw)) = tmp.u;
            }
        }
    };

    f32x4 acc[4][4];
#pragma unroll
    for (int mf = 0; mf < 4; ++mf)
#pragma unroll
        for (int nf = 0; nf < 4; ++nf)
            acc[mf][nf] = (f32x4){0.f, 0.f, 0.f, 0.f};

    // ---- prologue: kern stage 0 async + input half 0, one barrier
    stage_kern(0, 0);
    stage_input(0);
    __syncthreads();

#pragma unroll
    for (int sg = 0; sg < 10; ++sg) {
        const int buf = sg & 1;
        if (sg < 9) stage_kern(sg + 1, buf ^ 1);

        const int jj = sg % 5;
        const int ntap = (jj == 4) ? 1 : 2;
#pragma unroll
        for (int tt = 0; tt < 2; ++tt) {
            if (tt >= ntap) break;
            const int p = 2 * jj + tt;
            const int kh = p / 3, kw = p - kh * 3;

            bf16x8 Kf[4];
#pragma unroll
            for (int nf = 0; nf < 4; ++nf) {
                const int co = nf * 16 + l15;
                Kf[nf] = *(const bf16x8*)((const char*)kn_lds +
                          ((buf << 13) + (tt << 12) + (co << 6) +
                           ((hi4 << 4) ^ (((co >> 1) & 3) << 4))));
            }

            const int q = l15 + kw;
#pragma unroll
            for (int mf = 0; mf < 4; ++mf) {
                const int r = wv * 4 + mf + kh;
                const int px = r * 18 + q;
                bf16x8 Af = *(const bf16x8*)((const char*)in_lds +
                              ((px << 6) + ((hi4 << 4) ^ (((px >> 1) & 3) << 4))));
#pragma unroll
                for (int nf = 0; nf < 4; ++nf)
                    acc[mf][nf] = __builtin_amdgcn_mfma_f32_16x16x32_bf16(
                        Kf[nf], Af, acc[mf][nf], 0, 0, 0);
            }
        }

        if (sg == 4) {
            // all waves done with half-0 input; restage with half 1
            __syncthreads();
            stage_input(1);
        }
        __syncthreads();
    }

    // ---- LDS-transpose epilogue (per-wave, no block barrier needed):
    // wave region = 4 KB at in_lds + wv*4096, rows = 16 pixels x 256 B,
    // swizzle chunk16 ^= (row&7)<<4 (2-way max = free).
    // Then 4 NT stores/mf, each 1 KB fully contiguous (4 px rows x 256 B).
    char* ep = (char*)in_lds + (wv << 12);
#pragma unroll
    for (int mf = 0; mf < 4; ++mf) {
        const int iloc = wv * 4 + mf;
        const size_t rowoff = ((size_t)b << 16) +
                              (size_t)(gi * 128 + i0 + iloc) * 256 + (size_t)(gj * 128 + j0);
        // scatter: lane(l15,hi4) holds co = nf*16+hi4*4+reg at pixel l15
#pragma unroll
        for (int nf = 0; nf < 4; ++nf) {
            const int off = (nf * 64 + hi4 * 16) ^ ((l15 & 7) << 4);
            *(f32x4*)(ep + l15 * 256 + off) = acc[mf][nf];
        }
        asm volatile("s_waitcnt lgkmcnt(0)" ::: "memory");
        __builtin_amdgcn_sched_barrier(0);
        // gather: lane(l15,hi4) reads co-chunk l15 of pixel t*4+hi4
#pragma unroll
        for (int t = 0; t < 4; ++t) {
            const int px = t * 4 + hi4;
            f32x4 vv4 = *(const f32x4*)(ep + px * 256 + ((l15 << 4) ^ ((px & 7) << 4)));
            __builtin_nontemporal_store(vv4, (f32x4*)(out + (rowoff + px) * 64 + l15 * 4));
        }
        asm volatile("s_waitcnt lgkmcnt(0)" ::: "memory");
        __builtin_amdgcn_sched_barrier(0);
    }
}

// ---------------------------------------------------------------------------
extern "C" void kernel_launch(void* const* d_in, const int* in_sizes, int n_in,
                              void* d_out, int out_size, void* d_ws, size_t ws_size,
                              hipStream_t stream)
{
    const float* x      = (const float*)d_in[0];
    const float* conv_w = (const float*)d_in[1];
    const float* qkv_w  = (const float*)d_in[2];
    const float* qkv_b  = (const float*)d_in[3];
    const float* proj_w = (const float*)d_in[4];
    const float* proj_b = (const float*)d_in[5];
    const float* se_w1  = (const float*)d_in[6];
    const float* se_b1  = (const float*)d_in[7];
    const float* se_w2  = (const float*)d_in[8];
    const float* se_b2  = (const float*)d_in[9];
    float* out = (float*)d_out;

    float* qv = (float*)d_ws;            // 147456 f
    float* kv = qv + 147456;             // 147456 f
    float* vv = kv + 147456;             // 147456 f
    float* ao = vv + 147456;             // 147456 f
    ushort* kb = (ushort*)(ao + 147456); // 147456 u16  (total ~2.6 MB)

    hipLaunchKernelGGL(qkv_kernel, dim3(2304), dim3(192), 0, stream,
                       conv_w, qkv_w, qkv_b, qv, kv, vv);
    hipLaunchKernelGGL(attn_kernel, dim3(512), dim3(64), 0, stream, qv, kv, vv, ao);
    hipLaunchKernelGGL(proj_se_kernel, dim3(256), dim3(64), 0, stream,
                       ao, proj_w, proj_b, se_w1, se_b1, se_w2, se_b2, kb);
    hipLaunchKernelGGL(conv_kernel, dim3(2048), dim3(256), 0, stream, x, kb, out);
}

// Round 5
// 94.416 us; speedup vs baseline: 1.5683x; 1.5683x over previous
//
#include <hip/hip_runtime.h>
#include <hip/hip_bf16.h>

typedef __bf16 bf16x8 __attribute__((ext_vector_type(8)));
typedef float  f32x4  __attribute__((ext_vector_type(4)));

// ---------------------------------------------------------------------------
// Stage 1: qkv = kern_tok @ qkv_w + qkv_b ; split into q(scaled),k,v
// ---------------------------------------------------------------------------
__global__ __launch_bounds__(192) void qkv_kernel(
    const float* __restrict__ conv_w, const float* __restrict__ qkv_w,
    const float* __restrict__ qkv_b,
    float* __restrict__ qv, float* __restrict__ kvv, float* __restrict__ vv)
{
    __shared__ float tok[64];
    const int bid = blockIdx.x;          // co*36 + s
    const int co = bid / 36, s = bid - co * 36;
    const int w = s / 9, p = s - w * 9;
    const int t = threadIdx.x;           // 192
    if (t < 64) tok[t] = conv_w[(((w * 64 + co) * 64 + t) * 9) + p];
    __syncthreads();
    float acc = qkv_b[t];
#pragma unroll 8
    for (int ci = 0; ci < 64; ++ci) acc += tok[ci] * qkv_w[ci * 192 + t];
    const int trip = t >> 6, rem = t & 63, h = rem >> 3, d = rem & 7;
    if (trip == 0) acc *= 0.35355339059327373f;   // hd^-0.5, hd=8
    float* dst = (trip == 0) ? qv : ((trip == 1) ? kvv : vv);
    dst[((co * 8 + h) * 36 + s) * 8 + d] = acc;
}

// ---------------------------------------------------------------------------
// Stage 2: attention per (co, head): softmax(q k^T) v  -> ao[co][s][h*8+d]
// ---------------------------------------------------------------------------
__global__ __launch_bounds__(64) void attn_kernel(
    const float* __restrict__ qv, const float* __restrict__ kvv,
    const float* __restrict__ vv, float* __restrict__ ao)
{
    __shared__ float kl[288], vl[288];
    const int bid = blockIdx.x;          // co*8 + h
    const int t = threadIdx.x;           // 64
    const float* kb = kvv + bid * 288;
    const float* vb = vv + bid * 288;
    for (int i = t; i < 288; i += 64) { kl[i] = kb[i]; vl[i] = vb[i]; }
    __syncthreads();
    if (t < 36) {
        float q[8];
        const float* qb = qv + bid * 288 + t * 8;
#pragma unroll
        for (int d = 0; d < 8; ++d) q[d] = qb[d];
        float sc[36];
        float mx = -1e30f;
#pragma unroll
        for (int u = 0; u < 36; ++u) {
            float a = 0.f;
#pragma unroll
            for (int d = 0; d < 8; ++d) a += q[d] * kl[u * 8 + d];
            sc[u] = a;
            mx = fmaxf(mx, a);
        }
        float sum = 0.f;
        float o[8] = {0.f,0.f,0.f,0.f,0.f,0.f,0.f,0.f};
#pragma unroll
        for (int u = 0; u < 36; ++u) {
            float e = expf(sc[u] - mx);
            sum += e;
#pragma unroll
            for (int d = 0; d < 8; ++d) o[d] += e * vl[u * 8 + d];
        }
        const float inv = 1.0f / sum;
        const int co = bid >> 3, h = bid & 7;
        float* dst = ao + (co * 36 + t) * 64 + h * 8;
#pragma unroll
        for (int d = 0; d < 8; ++d) dst[d] = o[d] * inv;
    }
}

// ---------------------------------------------------------------------------
// Stage 3: proj + SE + write bf16 kernels.
// kout layout: [((h*4 + w)*9 + p)][co][ci32]  (4 KB chunks = one
// (tap, ci-half); conv stages exactly one chunk per pipeline stage).
// ---------------------------------------------------------------------------
__global__ __launch_bounds__(64) void proj_se_kernel(
    const float* __restrict__ ao, const float* __restrict__ proj_w,
    const float* __restrict__ proj_b,
    const float* __restrict__ se_w1, const float* __restrict__ se_b1,
    const float* __restrict__ se_w2, const float* __restrict__ se_b2,
    ushort* __restrict__ kout)
{
    __shared__ float al[9][64];
    __shared__ float pool[64];
    __shared__ float hb[4];
    const int bid = blockIdx.x;          // w*64 + co
    const int w = bid >> 6, co = bid & 63;
    const int t = threadIdx.x;           // 64 (= ci)
    for (int i = t; i < 576; i += 64) {
        int p = i >> 6, j = i & 63;
        al[p][j] = ao[(co * 36 + w * 9 + p) * 64 + j];
    }
    __syncthreads();
    float kv[9];
#pragma unroll
    for (int p = 0; p < 9; ++p) {
        float a = proj_b[t];
#pragma unroll 8
        for (int j = 0; j < 64; ++j) a += al[p][j] * proj_w[j * 64 + t];
        kv[p] = a;
    }
    float pl = 0.f;
#pragma unroll
    for (int p = 0; p < 9; ++p) pl += kv[p];
    pool[t] = pl * (1.0f / 9.0f);
    __syncthreads();
    if (t < 4) {
        float hh = se_b1[w * 4 + t];
#pragma unroll 8
        for (int c = 0; c < 64; ++c) hh += pool[c] * se_w1[(w * 4 + t) * 64 + c];
        hb[t] = fmaxf(hh, 0.0f);
    }
    __syncthreads();
    float z = se_b2[w * 64 + t];
#pragma unroll
    for (int d = 0; d < 4; ++d) z += hb[d] * se_w2[(w * 64 + t) * 4 + d];
    const float sg = 1.0f / (1.0f + expf(-z));
    const int hhalf = t >> 5, ci32 = t & 31;
#pragma unroll
    for (int p = 0; p < 9; ++p) {
        __hip_bfloat16 hv = __float2bfloat16(kv[p] * sg);
        kout[(((hhalf * 4 + w) * 9) + p) * 2048 + co * 32 + ci32] = *(const ushort*)&hv;
    }
}

// ---------------------------------------------------------------------------
// Stage 4: dynamic per-window 3x3 conv, implicit GEMM, bf16 MFMA.
//
// Round-5 restructure. Model from R0-R4: conv dur = hbm_bytes / realized_BW,
// realized BW set by load concurrency (duty cycle), NOT by the MFMA loop
// (MfmaUtil ~10%, VALUBusy ~9% in all rounds). So: minimize bytes (R0's
// traffic profile was ideal: 78 MB FETCH / 131 MB WRITE) while keeping
// concurrency (R3/R4's batched staging + occupancy).
//  - Single FULL-channel input staging (18x18x64 bf16 = 41.5 KB, R0's
//    proven 0-conflict col-XOR swizzle): x read ONCE per block, no
//    mid-kernel restage burst. Two batches of ~11 unconditional clamped
//    float4 loads keep ~11 KB/wave in flight.
//  - kern dbuf 2x4 KB (18 stages of one (tap,ci-half), one global_load_lds
//    per wave per stage, R4's proven source-pre-swizzle). LDS total
//    49.7 KB -> 3 blocks/CU (12 waves).
//  - PLAIN stores (no NT) through the LDS-transpose epilogue: 1 KB
//    contiguous per wave-instruction AND L2 write-combining (R4's NT gave
//    WRITE=2.37x ideal; R0's cached full-line stores gave 1.0x).
//  - XCD-chunked remap kept (R3: best FETCH).
// ---------------------------------------------------------------------------
__global__ __launch_bounds__(256, 3) void conv_kernel(
    const float* __restrict__ x, const ushort* __restrict__ kern,
    float* __restrict__ out)
{
    __shared__ alignas(16) ushort in_lds[18 * 18 * 64];   // 41472 B
    __shared__ alignas(16) ushort kn_lds[2 * 2048];       // 8192 B (2 x 4KB)

    const int tid = threadIdx.x;

    // ---- XCD-chunked bijective remap: XCD k processes nb in [k*256,(k+1)*256)
    const int bid = blockIdx.x;                 // 0..2047, xcd = bid & 7
    const int nb  = ((bid & 7) << 8) + (bid >> 3);
    const int bz  = nb >> 6;                    // (w*8+b), 4 per XCD
    const int rem = nb & 63;
    const int i0  = (rem >> 3) << 4;
    const int j0  = (rem & 7) << 4;
    const int w = bz >> 3, b = bz & 7;
    const int gi = w >> 1, gj = w & 1;

    const int wv   = tid >> 6;
    const int lane = tid & 63;
    const int l15  = lane & 15;
    const int hi4  = lane >> 4;        // 0..3

    // ---- async kern stage: stage s = (p = s>>1, half = s&1) -> one 4 KB
    // chunk at kern + (((half*4+w)*9)+p)*4096. Linear LDS dest; read-side
    // swizzle realized by pre-swizzling the GLOBAL source (both-sides rule).
    const char* kern_b = (const char*)kern;
    const int ksrc = (lane << 4) ^ (((lane >> 3) & 3) << 4);
    auto stage_kern = [&](int s, int buf) {
        const int p = s >> 1, hh = s & 1;
        const char* gs = kern_b + ((size_t)((((hh * 4 + w) * 9)) + p) << 12);
        __builtin_amdgcn_global_load_lds(
            (const __attribute__((address_space(1))) unsigned int*)(gs + (wv << 10) + ksrc),
            (__attribute__((address_space(3))) unsigned int*)
                ((char*)kn_lds + (buf << 12) + (wv << 10)),
            16, 0, 0);
    };

    // ---- input staging, FULL 64 channels: 18x18 px * 128 B.
    // 16 thr/px (4 ch each); 21 px-iterations split into 2 batches so
    // ~11 float4 loads are in flight before any cvt/ds_write consumes them.
    // LDS position: (pp<<7) + ((cc*2) ^ ((q&7)<<4))  [R0's 0-conflict swizzle]
    {
        const int cc = (tid & 15) << 2;    // channel 0..60
        const int p0 = tid >> 4;           // 0..15
#pragma unroll
        for (int half = 0; half < 2; ++half) {
            const int kbeg = half ? 11 : 0;
            const int kend = half ? 21 : 11;
            float4 v[11];
            unsigned okm = 0;
#pragma unroll
            for (int k = kbeg; k < kend; ++k) {
                const int pp = p0 + (k << 4);          // <= 335
                const int ppc = pp < 323 ? pp : 323;
                const int r = ppc / 18, q = ppc - r * 18;
                const int iy = i0 - 1 + r, jx = j0 - 1 + q;
                const bool ok = (pp < 324) & (iy >= 0) & (iy < 128) & (jx >= 0) & (jx < 128);
                const int iyc = iy < 0 ? 0 : (iy > 127 ? 127 : iy);
                const int jxc = jx < 0 ? 0 : (jx > 127 ? 127 : jx);
                const size_t xi = (((size_t)b << 16) +
                                   (size_t)(gi * 128 + iyc) * 256 + (size_t)(gj * 128 + jxc)) * 64 + cc;
                v[k - kbeg] = *(const float4*)(x + xi);
                okm |= (unsigned)ok << (k - kbeg);
            }
            if (half == 0) stage_kern(0, 0);   // overlap kern fetch with batch A
#pragma unroll
            for (int k = kbeg; k < kend; ++k) {
                const int pp = p0 + (k << 4);
                if (pp < 324) {
                    const int r = pp / 18, q = pp - r * 18;
                    float4 z = (okm >> (k - kbeg)) & 1 ? v[k - kbeg]
                                                       : make_float4(0.f, 0.f, 0.f, 0.f);
                    union { ushort4 u; ushort h4[4]; } tmp;
                    __hip_bfloat16 b0 = __float2bfloat16(z.x); tmp.h4[0] = *(const ushort*)&b0;
                    __hip_bfloat16 b1 = __float2bfloat16(z.y); tmp.h4[1] = *(const ushort*)&b1;
                    __hip_bfloat16 b2 = __float2bfloat16(z.z); tmp.h4[2] = *(const ushort*)&b2;
                    __hip_bfloat16 b3 = __float2bfloat16(z.w); tmp.h4[3] = *(const ushort*)&b3;
                    *(ushort4*)((char*)in_lds +
                        ((pp << 7) + ((cc << 1) ^ ((q & 7) << 4)))) = tmp.u;
                }
            }
        }
    }

    f32x4 acc[4][4];
#pragma unroll
    for (int mf = 0; mf < 4; ++mf)
#pragma unroll
        for (int nf = 0; nf < 4; ++nf)
            acc[mf][nf] = (f32x4){0.f, 0.f, 0.f, 0.f};

    __syncthreads();     // drains staging ds_writes + kern global_load_lds

#pragma unroll
    for (int s = 0; s < 18; ++s) {
        const int buf = s & 1;
        if (s < 17) stage_kern(s + 1, buf ^ 1);

        const int p = s >> 1, hh = s & 1;
        const int kh = p / 3, kw = p - kh * 3;

        // kern fragments: co = nf*16+l15, ci-chunk hi4 within this half
        bf16x8 Kf[4];
#pragma unroll
        for (int nf = 0; nf < 4; ++nf) {
            const int co = nf * 16 + l15;
            Kf[nf] = *(const bf16x8*)((const char*)kn_lds +
                      ((buf << 12) + (co << 6) +
                       ((hi4 << 4) ^ (((co >> 1) & 3) << 4))));
        }

        const int q = l15 + kw;
        const int swz = (q & 7) << 4;
        const int c2 = (hh << 6) | (hi4 << 4);
#pragma unroll
        for (int mf = 0; mf < 4; ++mf) {
            const int r = wv * 4 + mf + kh;
            bf16x8 Af = *(const bf16x8*)((const char*)in_lds +
                          (((r * 18 + q) << 7) + (c2 ^ swz)));
#pragma unroll
            for (int nf = 0; nf < 4; ++nf)
                acc[mf][nf] = __builtin_amdgcn_mfma_f32_16x16x32_bf16(
                    Kf[nf], Af, acc[mf][nf], 0, 0, 0);
        }
        __syncthreads();
    }

    // ---- LDS-transpose epilogue (wave-private 4 KB region; all in_lds
    // reads finished at the final loop barrier). Plain cached stores,
    // 1 KB contiguous per wave-instruction.
    char* ep = (char*)in_lds + (wv << 12);
#pragma unroll
    for (int mf = 0; mf < 4; ++mf) {
        const int iloc = wv * 4 + mf;
        const size_t rowoff = ((size_t)b << 16) +
                              (size_t)(gi * 128 + i0 + iloc) * 256 + (size_t)(gj * 128 + j0);
        // scatter: lane(l15,hi4) holds co = nf*16+hi4*4+reg at pixel l15
#pragma unroll
        for (int nf = 0; nf < 4; ++nf) {
            const int off = (nf * 64 + hi4 * 16) ^ ((l15 & 7) << 4);
            *(f32x4*)(ep + l15 * 256 + off) = acc[mf][nf];
        }
        // gather: lane(l15,hi4) reads co-chunk l15 of pixel t*4+hi4
#pragma unroll
        for (int t = 0; t < 4; ++t) {
            const int px = t * 4 + hi4;
            f32x4 vv4 = *(const f32x4*)(ep + px * 256 + ((l15 << 4) ^ ((px & 7) << 4)));
            *(f32x4*)(out + (rowoff + px) * 64 + l15 * 4) = vv4;
        }
    }
}

// ---------------------------------------------------------------------------
extern "C" void kernel_launch(void* const* d_in, const int* in_sizes, int n_in,
                              void* d_out, int out_size, void* d_ws, size_t ws_size,
                              hipStream_t stream)
{
    const float* x      = (const float*)d_in[0];
    const float* conv_w = (const float*)d_in[1];
    const float* qkv_w  = (const float*)d_in[2];
    const float* qkv_b  = (const float*)d_in[3];
    const float* proj_w = (const float*)d_in[4];
    const float* proj_b = (const float*)d_in[5];
    const float* se_w1  = (const float*)d_in[6];
    const float* se_b1  = (const float*)d_in[7];
    const float* se_w2  = (const float*)d_in[8];
    const float* se_b2  = (const float*)d_in[9];
    float* out = (float*)d_out;

    float* qv = (float*)d_ws;            // 147456 f
    float* kv = qv + 147456;             // 147456 f
    float* vv = kv + 147456;             // 147456 f
    float* ao = vv + 147456;             // 147456 f
    ushort* kb = (ushort*)(ao + 147456); // 147456 u16  (total ~2.6 MB)

    hipLaunchKernelGGL(qkv_kernel, dim3(2304), dim3(192), 0, stream,
                       conv_w, qkv_w, qkv_b, qv, kv, vv);
    hipLaunchKernelGGL(attn_kernel, dim3(512), dim3(64), 0, stream, qv, kv, vv, ao);
    hipLaunchKernelGGL(proj_se_kernel, dim3(256), dim3(64), 0, stream,
                       ao, proj_w, proj_b, se_w1, se_b1, se_w2, se_b2, kb);
    hipLaunchKernelGGL(conv_kernel, dim3(2048), dim3(256), 0, stream, x, kb, out);
}

// Round 6
// 84.232 us; speedup vs baseline: 1.7579x; 1.1209x over previous
//
#include <hip/hip_runtime.h>
#include <hip/hip_bf16.h>

typedef __bf16 bf16x8 __attribute__((ext_vector_type(8)));
typedef float  f32x4  __attribute__((ext_vector_type(4)));

// ---------------------------------------------------------------------------
// Stage 1: qkv = kern_tok @ qkv_w + qkv_b ; split into q(scaled),k,v
// ---------------------------------------------------------------------------
__global__ __launch_bounds__(192) void qkv_kernel(
    const float* __restrict__ conv_w, const float* __restrict__ qkv_w,
    const float* __restrict__ qkv_b,
    float* __restrict__ qv, float* __restrict__ kvv, float* __restrict__ vv)
{
    __shared__ float tok[64];
    const int bid = blockIdx.x;          // co*36 + s
    const int co = bid / 36, s = bid - co * 36;
    const int w = s / 9, p = s - w * 9;
    const int t = threadIdx.x;           // 192
    if (t < 64) tok[t] = conv_w[(((w * 64 + co) * 64 + t) * 9) + p];
    __syncthreads();
    float acc = qkv_b[t];
#pragma unroll 8
    for (int ci = 0; ci < 64; ++ci) acc += tok[ci] * qkv_w[ci * 192 + t];
    const int trip = t >> 6, rem = t & 63, h = rem >> 3, d = rem & 7;
    if (trip == 0) acc *= 0.35355339059327373f;   // hd^-0.5, hd=8
    float* dst = (trip == 0) ? qv : ((trip == 1) ? kvv : vv);
    dst[((co * 8 + h) * 36 + s) * 8 + d] = acc;
}

// ---------------------------------------------------------------------------
// Stage 2: attention per (co, head): softmax(q k^T) v  -> ao[co][s][h*8+d]
// ---------------------------------------------------------------------------
__global__ __launch_bounds__(64) void attn_kernel(
    const float* __restrict__ qv, const float* __restrict__ kvv,
    const float* __restrict__ vv, float* __restrict__ ao)
{
    __shared__ float kl[288], vl[288];
    const int bid = blockIdx.x;          // co*8 + h
    const int t = threadIdx.x;           // 64
    const float* kb = kvv + bid * 288;
    const float* vb = vv + bid * 288;
    for (int i = t; i < 288; i += 64) { kl[i] = kb[i]; vl[i] = vb[i]; }
    __syncthreads();
    if (t < 36) {
        float q[8];
        const float* qb = qv + bid * 288 + t * 8;
#pragma unroll
        for (int d = 0; d < 8; ++d) q[d] = qb[d];
        float sc[36];
        float mx = -1e30f;
#pragma unroll
        for (int u = 0; u < 36; ++u) {
            float a = 0.f;
#pragma unroll
            for (int d = 0; d < 8; ++d) a += q[d] * kl[u * 8 + d];
            sc[u] = a;
            mx = fmaxf(mx, a);
        }
        float sum = 0.f;
        float o[8] = {0.f,0.f,0.f,0.f,0.f,0.f,0.f,0.f};
#pragma unroll
        for (int u = 0; u < 36; ++u) {
            float e = expf(sc[u] - mx);
            sum += e;
#pragma unroll
            for (int d = 0; d < 8; ++d) o[d] += e * vl[u * 8 + d];
        }
        const float inv = 1.0f / sum;
        const int co = bid >> 3, h = bid & 7;
        float* dst = ao + (co * 36 + t) * 64 + h * 8;
#pragma unroll
        for (int d = 0; d < 8; ++d) dst[d] = o[d] * inv;
    }
}

// ---------------------------------------------------------------------------
// Stage 3: proj + SE + write bf16 kernels.
// kout layout: [((h*4 + w)*9 + p)][co][ci32]  (4 KB chunks = one
// (tap, ci-half); conv stages exactly one chunk per pipeline stage).
// ---------------------------------------------------------------------------
__global__ __launch_bounds__(64) void proj_se_kernel(
    const float* __restrict__ ao, const float* __restrict__ proj_w,
    const float* __restrict__ proj_b,
    const float* __restrict__ se_w1, const float* __restrict__ se_b1,
    const float* __restrict__ se_w2, const float* __restrict__ se_b2,
    ushort* __restrict__ kout)
{
    __shared__ float al[9][64];
    __shared__ float pool[64];
    __shared__ float hb[4];
    const int bid = blockIdx.x;          // w*64 + co
    const int w = bid >> 6, co = bid & 63;
    const int t = threadIdx.x;           // 64 (= ci)
    for (int i = t; i < 576; i += 64) {
        int p = i >> 6, j = i & 63;
        al[p][j] = ao[(co * 36 + w * 9 + p) * 64 + j];
    }
    __syncthreads();
    float kv[9];
#pragma unroll
    for (int p = 0; p < 9; ++p) {
        float a = proj_b[t];
#pragma unroll 8
        for (int j = 0; j < 64; ++j) a += al[p][j] * proj_w[j * 64 + t];
        kv[p] = a;
    }
    float pl = 0.f;
#pragma unroll
    for (int p = 0; p < 9; ++p) pl += kv[p];
    pool[t] = pl * (1.0f / 9.0f);
    __syncthreads();
    if (t < 4) {
        float hh = se_b1[w * 4 + t];
#pragma unroll 8
        for (int c = 0; c < 64; ++c) hh += pool[c] * se_w1[(w * 4 + t) * 64 + c];
        hb[t] = fmaxf(hh, 0.0f);
    }
    __syncthreads();
    float z = se_b2[w * 64 + t];
#pragma unroll
    for (int d = 0; d < 4; ++d) z += hb[d] * se_w2[(w * 64 + t) * 4 + d];
    const float sg = 1.0f / (1.0f + expf(-z));
    const int hhalf = t >> 5, ci32 = t & 31;
#pragma unroll
    for (int p = 0; p < 9; ++p) {
        __hip_bfloat16 hv = __float2bfloat16(kv[p] * sg);
        kout[(((hhalf * 4 + w) * 9) + p) * 2048 + co * 32 + ci32] = *(const ushort*)&hv;
    }
}

// ---------------------------------------------------------------------------
// Stage 4: dynamic per-window 3x3 conv, implicit GEMM, bf16 MFMA.
//
// Round-6: counted-vmcnt kern pipeline (T3/T4). R5's bytes are ideal
// (FETCH 75 MB, WRITE ~ideal, conflicts 0) but every one of the 18 stages
// ended in __syncthreads => s_waitcnt vmcnt(0) => the kern global_load_lds
// issued that stage was fully drained the same stage (latency exposed 18x,
// all 4 waves aligned on the stall). Now:
//  - kern TRIPLE buffer (3 x 4 KB), raw s_barrier, asm s_waitcnt vmcnt(1)
//    (never 0 in the loop). Per stage s: vmcnt(1) [my load(s) retired;
//    in-order retirement] -> s_barrier [all waves' load(s) in LDS, all done
//    compute(s-1)] -> compute(s) from buf[s%3] -> issue load(s+2) into
//    buf[(s+2)%3] (safe: last read at s-1, all waves past it). Load gets
//    ~2 stages of latency window. ONE full drain total (prologue).
//  - sched_barrier(0) after each asm wait (rule: hipcc hoists reg-only ops
//    past asm waits otherwise).
//  - LDS 41472 + 12288 = 53760 B; 3*53760 = 161280 <= 163840 -> still
//    3 blocks/CU.
//  - Staging depth 21: all 21 clamped float4 loads issued (static v[21],
//    ~84 transient VGPR, fits (256,3) budget) before the cvt/write pass.
//  - Explicit lgkmcnt(0)+barrier before the epilogue (loop no longer ends
//    with a barrier).
// ---------------------------------------------------------------------------
__global__ __launch_bounds__(256, 3) void conv_kernel(
    const float* __restrict__ x, const ushort* __restrict__ kern,
    float* __restrict__ out)
{
    __shared__ alignas(16) ushort in_lds[18 * 18 * 64];   // 41472 B
    __shared__ alignas(16) ushort kn_lds[3 * 2048];       // 12288 B (3 x 4KB)

    const int tid = threadIdx.x;

    // ---- XCD-chunked bijective remap: XCD k processes nb in [k*256,(k+1)*256)
    const int bid = blockIdx.x;                 // 0..2047, xcd = bid & 7
    const int nb  = ((bid & 7) << 8) + (bid >> 3);
    const int bz  = nb >> 6;                    // (w*8+b), 4 per XCD
    const int rem = nb & 63;
    const int i0  = (rem >> 3) << 4;
    const int j0  = (rem & 7) << 4;
    const int w = bz >> 3, b = bz & 7;
    const int gi = w >> 1, gj = w & 1;

    const int wv   = tid >> 6;
    const int lane = tid & 63;
    const int l15  = lane & 15;
    const int hi4  = lane >> 4;        // 0..3

    // ---- async kern stage: stage s = (p = s>>1, half = s&1) -> one 4 KB
    // chunk at kern + (((half*4+w)*9)+p)*4096. Linear LDS dest; read-side
    // swizzle realized by pre-swizzling the GLOBAL source (both-sides rule).
    const char* kern_b = (const char*)kern;
    const int ksrc = (lane << 4) ^ (((lane >> 3) & 3) << 4);
    auto stage_kern = [&](int s, int buf) {
        const int p = s >> 1, hh = s & 1;
        const char* gs = kern_b + ((size_t)((((hh * 4 + w) * 9)) + p) << 12);
        __builtin_amdgcn_global_load_lds(
            (const __attribute__((address_space(1))) unsigned int*)(gs + (wv << 10) + ksrc),
            (__attribute__((address_space(3))) unsigned int*)
                ((char*)kn_lds + (buf << 12) + (wv << 10)),
            16, 0, 0);
    };

    // ---- prologue: issue kern stages 0,1 first (they fly under the input
    // staging burst), then stage the FULL input tile, then ONE full drain.
    stage_kern(0, 0);
    stage_kern(1, 1);

    // input staging, FULL 64 channels: 18x18 px * 128 B, 16 thr/px (4 ch).
    // All 21 clamped loads issued before the cvt/write pass (deep flight).
    // LDS position: (pp<<7) + ((cc*2) ^ ((q&7)<<4))  [0-conflict swizzle]
    {
        const int cc = (tid & 15) << 2;    // channel 0..60
        const int p0 = tid >> 4;           // 0..15
        float4 v[21];
        unsigned okm = 0;
#pragma unroll
        for (int k = 0; k < 21; ++k) {
            const int pp = p0 + (k << 4);          // <= 335
            const int ppc = pp < 323 ? pp : 323;
            const int r = ppc / 18, q = ppc - r * 18;
            const int iy = i0 - 1 + r, jx = j0 - 1 + q;
            const bool ok = (pp < 324) & (iy >= 0) & (iy < 128) & (jx >= 0) & (jx < 128);
            const int iyc = iy < 0 ? 0 : (iy > 127 ? 127 : iy);
            const int jxc = jx < 0 ? 0 : (jx > 127 ? 127 : jx);
            const size_t xi = (((size_t)b << 16) +
                               (size_t)(gi * 128 + iyc) * 256 + (size_t)(gj * 128 + jxc)) * 64 + cc;
            v[k] = *(const float4*)(x + xi);
            okm |= (unsigned)ok << k;
        }
#pragma unroll
        for (int k = 0; k < 21; ++k) {
            const int pp = p0 + (k << 4);
            if (pp < 324) {
                const int r = pp / 18, q = pp - r * 18;
                float4 z = (okm >> k) & 1 ? v[k] : make_float4(0.f, 0.f, 0.f, 0.f);
                union { ushort4 u; ushort h4[4]; } tmp;
                __hip_bfloat16 b0 = __float2bfloat16(z.x); tmp.h4[0] = *(const ushort*)&b0;
                __hip_bfloat16 b1 = __float2bfloat16(z.y); tmp.h4[1] = *(const ushort*)&b1;
                __hip_bfloat16 b2 = __float2bfloat16(z.z); tmp.h4[2] = *(const ushort*)&b2;
                __hip_bfloat16 b3 = __float2bfloat16(z.w); tmp.h4[3] = *(const ushort*)&b3;
                *(ushort4*)((char*)in_lds +
                    ((pp << 7) + ((cc << 1) ^ ((q & 7) << 4)))) = tmp.u;
            }
        }
    }

    f32x4 acc[4][4];
#pragma unroll
    for (int mf = 0; mf < 4; ++mf)
#pragma unroll
        for (int nf = 0; nf < 4; ++nf)
            acc[mf][nf] = (f32x4){0.f, 0.f, 0.f, 0.f};

    __syncthreads();     // the ONE full drain: input ds_writes + kern 0,1

#pragma unroll
    for (int s = 0; s < 18; ++s) {
        // my load(s) retired when <=1 outstanding (only load(s+1) in flight;
        // load(s+2) not yet issued). vmem retires in order.
        asm volatile("s_waitcnt vmcnt(1)" ::: "memory");
        __builtin_amdgcn_sched_barrier(0);
        __builtin_amdgcn_s_barrier();      // all waves' load(s) in LDS
        __builtin_amdgcn_sched_barrier(0);

        const int buf = s % 3;
        const int p = s >> 1, hh = s & 1;
        const int kh = p / 3, kw = p - kh * 3;

        // kern fragments: co = nf*16+l15, ci-chunk hi4 within this half
        bf16x8 Kf[4];
#pragma unroll
        for (int nf = 0; nf < 4; ++nf) {
            const int co = nf * 16 + l15;
            Kf[nf] = *(const bf16x8*)((const char*)kn_lds +
                      ((buf << 12) + (co << 6) +
                       ((hi4 << 4) ^ (((co >> 1) & 3) << 4))));
        }

        const int q = l15 + kw;
        const int swz = (q & 7) << 4;
        const int c2 = (hh << 6) | (hi4 << 4);
#pragma unroll
        for (int mf = 0; mf < 4; ++mf) {
            const int r = wv * 4 + mf + kh;
            bf16x8 Af = *(const bf16x8*)((const char*)in_lds +
                          (((r * 18 + q) << 7) + (c2 ^ swz)));
#pragma unroll
            for (int nf = 0; nf < 4; ++nf)
                acc[mf][nf] = __builtin_amdgcn_mfma_f32_16x16x32_bf16(
                    Kf[nf], Af, acc[mf][nf], 0, 0, 0);
        }

        // issue load(s+2) into buf[(s+2)%3]: all waves passed this stage's
        // barrier, i.e. finished compute(s-1) = last readers of that buffer.
        if (s < 16) stage_kern(s + 2, (s + 2) % 3);
    }

    // ---- pre-epilogue barrier: my ds_reads retired (lgkm 0), then all
    // waves arrive => nobody still reads in_lds when we overwrite it.
    asm volatile("s_waitcnt lgkmcnt(0)" ::: "memory");
    __builtin_amdgcn_sched_barrier(0);
    __builtin_amdgcn_s_barrier();
    __builtin_amdgcn_sched_barrier(0);

    // ---- LDS-transpose epilogue (wave-private 4 KB region). Plain cached
    // stores, 1 KB contiguous per wave-instruction.
    char* ep = (char*)in_lds + (wv << 12);
#pragma unroll
    for (int mf = 0; mf < 4; ++mf) {
        const int iloc = wv * 4 + mf;
        const size_t rowoff = ((size_t)b << 16) +
                              (size_t)(gi * 128 + i0 + iloc) * 256 + (size_t)(gj * 128 + j0);
        // scatter: lane(l15,hi4) holds co = nf*16+hi4*4+reg at pixel l15
#pragma unroll
        for (int nf = 0; nf < 4; ++nf) {
            const int off = (nf * 64 + hi4 * 16) ^ ((l15 & 7) << 4);
            *(f32x4*)(ep + l15 * 256 + off) = acc[mf][nf];
        }
        // gather: lane(l15,hi4) reads co-chunk l15 of pixel t*4+hi4
#pragma unroll
        for (int t = 0; t < 4; ++t) {
            const int px = t * 4 + hi4;
            f32x4 vv4 = *(const f32x4*)(ep + px * 256 + ((l15 << 4) ^ ((px & 7) << 4)));
            *(f32x4*)(out + (rowoff + px) * 64 + l15 * 4) = vv4;
        }
    }
}

// ---------------------------------------------------------------------------
extern "C" void kernel_launch(void* const* d_in, const int* in_sizes, int n_in,
                              void* d_out, int out_size, void* d_ws, size_t ws_size,
                              hipStream_t stream)
{
    const float* x      = (const float*)d_in[0];
    const float* conv_w = (const float*)d_in[1];
    const float* qkv_w  = (const float*)d_in[2];
    const float* qkv_b  = (const float*)d_in[3];
    const float* proj_w = (const float*)d_in[4];
    const float* proj_b = (const float*)d_in[5];
    const float* se_w1  = (const float*)d_in[6];
    const float* se_b1  = (const float*)d_in[7];
    const float* se_w2  = (const float*)d_in[8];
    const float* se_b2  = (const float*)d_in[9];
    float* out = (float*)d_out;

    float* qv = (float*)d_ws;            // 147456 f
    float* kv = qv + 147456;             // 147456 f
    float* vv = kv + 147456;             // 147456 f
    float* ao = vv + 147456;             // 147456 f
    ushort* kb = (ushort*)(ao + 147456); // 147456 u16  (total ~2.6 MB)

    hipLaunchKernelGGL(qkv_kernel, dim3(2304), dim3(192), 0, stream,
                       conv_w, qkv_w, qkv_b, qv, kv, vv);
    hipLaunchKernelGGL(attn_kernel, dim3(512), dim3(64), 0, stream, qv, kv, vv, ao);
    hipLaunchKernelGGL(proj_se_kernel, dim3(256), dim3(64), 0, stream,
                       ao, proj_w, proj_b, se_w1, se_b1, se_w2, se_b2, kb);
    hipLaunchKernelGGL(conv_kernel, dim3(2048), dim3(256), 0, stream, x, kb, out);
}